// Round 4
// baseline (299.458 us; speedup 1.0000x reference)
//
#include <hip/hip_runtime.h>

// B=8, T=64, N=512, D=64, K=8 heads, d=8.
// One workgroup per (b,n) -- now 512 thr = 8 waves (vs 4). Wave pair
// m = w>>1 owns t-rows 16m..16m+15; sub-wave u = w&1 takes col-tiles
// {2u,2u+1} in GEMMs and heads {32u..32u+31} in attention.
// Rationale (r3 ablation): kernel is stall-bound at fixed occupancy --
// removing 35% of instructions changed nothing; time scales with resident
// waves. 512-thr blocks @ 36,864B LDS hit the 2048-thr/CU cap: 4 blocks x
// 8 waves = 32 waves/CU = 100% occupancy (was 16).

#define Bb 8
#define Tt 64
#define Nn 512
#define Dd 64

typedef unsigned short u16;
typedef unsigned int u32;
typedef __bf16 bf16x8 __attribute__((ext_vector_type(8)));
typedef float f32x4 __attribute__((ext_vector_type(4)));
typedef short s16x8 __attribute__((ext_vector_type(8)));
typedef u32 u32x4 __attribute__((ext_vector_type(4)));

// LDS stride in shorts: 72 = 36 dw == 4 (mod 32) -> bank-balanced b128 rows,
// rows 16B-aligned.
#define QS 72

// ws layout (u16): WtQ[64][128] @0, WtK @8192, WtV @16384,
//                  Wt1[64][64] @24576, Wt2 @28672. Total 32768 u16 = 64 KiB.
#define WSQ 0
#define WSK 8192
#define WSV 16384
#define WS1 24576
#define WS2 28672

__device__ inline u16 f2bf(float f) {             // fp32 -> bf16 RNE
    u32 x = __float_as_uint(f);
    x += 0x7fffu + ((x >> 16) & 1u);
    return (u16)(x >> 16);
}
__device__ inline bf16x8 ldf(const u16* p) { return *(const bf16x8*)p; }
__device__ inline bf16x8 zf8() {
    s16x8 z = {0, 0, 0, 0, 0, 0, 0, 0};
    return __builtin_bit_cast(bf16x8, z);
}
__device__ inline bf16x8 pack8(float4 a, float4 b) {
    s16x8 r;
    r[0] = (short)f2bf(a.x); r[1] = (short)f2bf(a.y);
    r[2] = (short)f2bf(a.z); r[3] = (short)f2bf(a.w);
    r[4] = (short)f2bf(b.x); r[5] = (short)f2bf(b.y);
    r[6] = (short)f2bf(b.z); r[7] = (short)f2bf(b.w);
    return __builtin_bit_cast(bf16x8, r);
}
// Token row permutation for kb storage (bits 5..0: b1 q1 q0 b0 r1 r0 ->
// b1 b0 q1 q0 r1 r0): score slot (ct,qd,r) then holds s = 8qd+4(ct&1)+r+32(ct>>1).
__device__ inline int kperm(int row) {
    return (row & 0x23) | ((row & 4) << 2) | ((row & 0x18) >> 1);
}

// 64x64 GEMM, sub-wave form: wave (m,u) computes rows 16m..16m+15, col-tiles
// ct in {2u, 2u+1}. A: registers (AREG) or LDS rows. B: global bf16
// Wt[col][KD] (L2-hot).
// MODE 0: relu -> bf16 LDS row-major; MODE 1: relu -> bf16 LDS transposed
// (O[col][row], vectorized ushort4); MODE 2: no relu -> fp32 global
// (row stride N*D); MODE 3: relu -> bf16 LDS rows permuted by kperm (kb).
template<int KD, int MODE, bool AREG>
__device__ inline void gemm(const bf16x8* afr,
                            const u16* aLds, int As,
                            const u16* __restrict__ WtG,
                            const float* __restrict__ bias,
                            u16* O, int Os, float* G,
                            int m, int u, int lane, float scale) {
    const int l15 = lane & 15, qd = lane >> 4;
    f32x4 acc[2] = {{0,0,0,0},{0,0,0,0}};
#pragma unroll
    for (int c = 0; c < KD / 32; ++c) {
        bf16x8 af = AREG ? afr[c]
                         : ldf(&aLds[(16 * m + l15) * As + c * 32 + qd * 8]);
#pragma unroll
        for (int j = 0; j < 2; ++j) {
            const int ct = 2 * u + j;
            bf16x8 bfr = *(const bf16x8*)&WtG[(16 * ct + l15) * KD + c * 32 + qd * 8];
            acc[j] = __builtin_amdgcn_mfma_f32_16x16x32_bf16(af, bfr, acc[j], 0, 0, 0);
        }
    }
#pragma unroll
    for (int j = 0; j < 2; ++j) {
        const int ct = 2 * u + j;
        const int col = 16 * ct + l15;
        const float bv = bias[col];
        if (MODE == 1) {
            ushort4 st;
            st.x = f2bf(fmaxf(acc[j][0] + bv, 0.f) * scale);
            st.y = f2bf(fmaxf(acc[j][1] + bv, 0.f) * scale);
            st.z = f2bf(fmaxf(acc[j][2] + bv, 0.f) * scale);
            st.w = f2bf(fmaxf(acc[j][3] + bv, 0.f) * scale);
            *(ushort4*)&O[col * Os + 16 * m + 4 * qd] = st;
        } else {
#pragma unroll
            for (int r = 0; r < 4; ++r) {
                const int row = 16 * m + 4 * qd + r;
                float v = acc[j][r] + bv;
                if (MODE != 2) v = fmaxf(v, 0.f);
                v *= scale;
                if (MODE == 0)      O[row * Os + col] = f2bf(v);
                else if (MODE == 3) O[kperm(row) * Os + col] = f2bf(v);
                else                G[(size_t)row * (Nn * Dd) + col] = v;
            }
        }
    }
}

// One-time weight transpose+convert: Wt[c][k] = bf16(W[k][c]).
__global__ __launch_bounds__(256)
void prep_w(const float* __restrict__ Wq, const float* __restrict__ Wk,
            const float* __restrict__ Wv, const float* __restrict__ W1,
            const float* __restrict__ W2, u16* __restrict__ ws) {
    int i = blockIdx.x * 256 + threadIdx.x;
    if (i < 24576) {                       // Wq/Wk/Wv: [128][64] each
        int m = i >> 13;
        int r = i & 8191;                  // r = k*64 + c (coalesced read)
        int k = r >> 6, c = r & 63;
        const float* W = (m == 0) ? Wq : (m == 1) ? Wk : Wv;
        ws[m * 8192 + c * 128 + k] = f2bf(W[r]);
    } else if (i < 32768) {                // W1/W2: [64][64] each
        int j = i - 24576;
        int m = j >> 12;
        int r = j & 4095;
        int k = r >> 6, c = r & 63;
        const float* W = (m == 0) ? W1 : W2;
        ws[24576 + m * 4096 + c * 64 + k] = f2bf(W[r]);
    }
}

__global__ __launch_bounds__(512, 8)
void ta_fused_kernel(const float* __restrict__ x,  const float* __restrict__ ste,
                     const float* __restrict__ bq, const float* __restrict__ bk,
                     const float* __restrict__ bv, const float* __restrict__ b1,
                     const float* __restrict__ b2, const u16* __restrict__ ws,
                     float* __restrict__ out) {
    // LDS map (shorts), 18432 total = 36,864 B (4 blocks/CU fits: 147KB):
    //   qb [64][72] @ 0      (FFN abuf overlays after barrier 2)
    //   kb [64][72] @ 4608   (rows kperm-permuted)
    //   vT [64][72] @ 9216   (vT[dim][s]; read-only after barrier 1)
    //   ao [64][72] @ 13824  (attention output)
    __shared__ __align__(16) u16 sm[18432];
    u16* qb = sm;
    u16* kb = sm + 4608;
    u16* vT = sm + 9216;
    u16* ao = sm + 13824;

    const int tid  = threadIdx.x;
    const int w    = tid >> 6;
    const int m    = w >> 1;                // row-stripe 0..3
    const int u    = w & 1;                 // sub-wave col/head split
    const int lane = tid & 63;
    const int l15  = lane & 15, qd = lane >> 4;
    const int bid  = blockIdx.x;
    const int b = bid >> 9, n = bid & 511;

    // ---- Phase 0: A-fragments (concat(x,ste) row 16m+l15) -> registers ----
    // (duplicated across the sub-wave pair; same cache lines, L1-absorbed)
    const int trow = 16 * m + l15;
    const float* xr = x   + (((size_t)b * Tt + trow) * Nn + n) * Dd;
    const float* sr = ste + (((size_t)b * Tt + trow) * Nn + n) * Dd;
    bf16x8 af[4];
#pragma unroll
    for (int c = 0; c < 2; ++c) {
        float4 p0 = *(const float4*)(xr + c * 32 + qd * 8);
        float4 p1 = *(const float4*)(xr + c * 32 + qd * 8 + 4);
        af[c] = pack8(p0, p1);
    }
#pragma unroll
    for (int c = 0; c < 2; ++c) {
        float4 p0 = *(const float4*)(sr + c * 32 + qd * 8);
        float4 p1 = *(const float4*)(sr + c * 32 + qd * 8 + 4);
        af[c + 2] = pack8(p0, p1);
    }

    // ---- Phase 1: QKV (B-fragments from global bf16 Wt, L2-hot) ----
    // 1/sqrt(8) folded into q.
    gemm<128, 0, true>(af, nullptr, 0, ws + WSQ, bq, qb, QS, nullptr, m, u, lane,
                       0.35355339059327373f);
    gemm<128, 3, true>(af, nullptr, 0, ws + WSK, bk, kb, QS, nullptr, m, u, lane, 1.f);
    gemm<128, 1, true>(af, nullptr, 0, ws + WSV, bv, vT, QS, nullptr, m, u, lane, 1.f);
    __syncthreads();   // barrier 1: qb/kb/vT read cross-wave below

    // ---- Phase 2: attention. Wave (m,u): t-rows 16m..16m+15, heads 4u..4u+3.
    const bf16x8 z8 = zf8();
    const int ctmax = (m >= 2) ? 3 : 1;     // causal tile skip
#pragma unroll 1
    for (int i = 0; i < 4; ++i) {
        const int h8 = 32 * u + 8 * i;
        // scores (swapped): sv[ct] = mfma(A=k-tile ct, B=q). Output col l15 =
        // t-local, slot (ct,qd,r) -> s = 8qd+4(ct&1)+r+32(ct>>1) via kperm.
        // K padded 8->32: both operands explicitly zeroed for qd>0.
        bf16x8 qfr = (qd == 0) ? ldf(&qb[(16 * m + l15) * QS + h8]) : z8;
        f32x4 sv[4] = {{0,0,0,0},{0,0,0,0},{0,0,0,0},{0,0,0,0}};
#pragma unroll
        for (int ct = 0; ct < 4; ++ct) {
            if (ct <= ctmax) {
                bf16x8 kfr = (qd == 0) ? ldf(&kb[(16 * ct + l15) * QS + h8]) : z8;
                sv[ct] = __builtin_amdgcn_mfma_f32_16x16x32_bf16(kfr, qfr, sv[ct], 0, 0, 0);
            }
        }
        // mask + exp in-register (scores small: no max-subtraction; masked
        // entries exactly 0), pack to bf16 pairs (P fragment).
        const int t = 16 * m + l15;
        float dsum = 0.f;
        u32 pk[8];
#pragma unroll
        for (int ct = 0; ct < 4; ++ct) {
            if (ct <= ctmax) {
                const int sbase = 8 * qd + 4 * (ct & 1) + 32 * (ct >> 1);
#pragma unroll
                for (int r = 0; r < 4; ++r) {
                    float e = (sbase + r <= t) ? __expf(sv[ct][r]) : 0.f;
                    sv[ct][r] = e;
                    dsum += e;
                }
                pk[2 * ct]     = (u32)f2bf(sv[ct][0]) | ((u32)f2bf(sv[ct][1]) << 16);
                pk[2 * ct + 1] = (u32)f2bf(sv[ct][2]) | ((u32)f2bf(sv[ct][3]) << 16);
            } else {
                pk[2 * ct] = 0; pk[2 * ct + 1] = 0;
            }
        }
        // full row-denominator for t = 16m+l15: partial + cross-quad butterfly
        dsum += __shfl_xor(dsum, 16, 64);
        dsum += __shfl_xor(dsum, 32, 64);

        // PV (swapped): o = mfma(A = V^T slice, B = P^T). A[row=l15] = V-col
        // for dim h8+(l15&7) (rows 8..15 duplicate 0..7, discarded); B col
        // l15 = t -> lane's own dsum normalizes its column.
        const int vrow = h8 + (l15 & 7);
        f32x4 o = {0, 0, 0, 0};
        {
            bf16x8 va0 = ldf(&vT[vrow * QS + 0 + qd * 8]);
            u32x4 pb0 = {pk[0], pk[1], pk[2], pk[3]};
            o = __builtin_amdgcn_mfma_f32_16x16x32_bf16(
                    va0, __builtin_bit_cast(bf16x8, pb0), o, 0, 0, 0);
        }
        if (m >= 2) {
            bf16x8 va1 = ldf(&vT[vrow * QS + 32 + qd * 8]);
            u32x4 pb1 = {pk[4], pk[5], pk[6], pk[7]};
            o = __builtin_amdgcn_mfma_f32_16x16x32_bf16(
                    va1, __builtin_bit_cast(bf16x8, pb1), o, 0, 0, 0);
        }
        // o[r] = out[t=16m+l15][h8 + ((4qd+r)&7)] unnormalized; qd>=2 lanes
        // hold duplicates of qd-2. One aligned ushort4 store per lane.
        float invd = __builtin_amdgcn_rcpf(dsum);
        if (qd < 2) {
            ushort4 st;
            st.x = f2bf(o[0] * invd);
            st.y = f2bf(o[1] * invd);
            st.z = f2bf(o[2] * invd);
            st.w = f2bf(o[3] * invd);
            *(ushort4*)&ao[(16 * m + l15) * QS + h8 + 4 * qd] = st;
        }
    }
    __syncthreads();   // barrier 2: ao cols are cross-sub-wave; qb now dead

    // ---- Phase 3: FFN ----
    u16* abuf = qb;    // overlay (qb dead after barrier 2)
    gemm<64, 0, false>(nullptr, ao, QS, ws + WS1, b1, abuf, QS, nullptr,
                       m, u, lane, 1.f);
    __syncthreads();   // barrier 3: abuf cols are cross-sub-wave
    float* ob = out + (((size_t)b * Tt) * Nn + n) * Dd;
    gemm<64, 2, false>(nullptr, abuf, QS, ws + WS2, b2, nullptr, 0, ob,
                       m, u, lane, 1.f);
}

extern "C" void kernel_launch(void* const* d_in, const int* in_sizes, int n_in,
                              void* d_out, int out_size, void* d_ws, size_t ws_size,
                              hipStream_t stream) {
    const float* x   = (const float*)d_in[0];
    const float* ste = (const float*)d_in[1];
    const float* Wq  = (const float*)d_in[2];
    const float* bq  = (const float*)d_in[3];
    const float* Wk  = (const float*)d_in[4];
    const float* bk  = (const float*)d_in[5];
    const float* Wv  = (const float*)d_in[6];
    const float* bv  = (const float*)d_in[7];
    const float* W1  = (const float*)d_in[8];
    const float* b1  = (const float*)d_in[9];
    const float* W2  = (const float*)d_in[10];
    const float* b2  = (const float*)d_in[11];
    float* out = (float*)d_out;
    u16* ws = (u16*)d_ws;

    hipLaunchKernelGGL(prep_w, dim3(128), dim3(256), 0, stream,
                       Wq, Wk, Wv, W1, W2, ws);
    hipLaunchKernelGGL(ta_fused_kernel, dim3(Bb * Nn), dim3(512), 0, stream,
                       x, ste, bq, bk, bv, b1, b2, ws, out);
}

// Round 5
// 286.679 us; speedup vs baseline: 1.0446x; 1.0446x over previous
//
#include <hip/hip_runtime.h>

// B=8, T=64, N=512, D=64, K=8 heads, d=8.
// One workgroup (256 thr = 4 waves) per (b,n). Full fusion.
// vs r3 (165us): latency-chain attack (r4 falsified occupancy theory):
//  - gemm: ALL B-fragment weight loads batched into registers BEFORE the
//    MFMA chain -> one vmem-latency round per gemm instead of ~4.
//  - attention: V loads hoisted to iter top (independent of P); next iter's
//    q/k fragments prefetched before the exp/pack/PV chain of the current
//    iter -> LDS latency hidden under VALU work.
// Structure otherwise identical to r3 (which passed, absmax 1.46e-3).

#define Bb 8
#define Tt 64
#define Nn 512
#define Dd 64

typedef unsigned short u16;
typedef unsigned int u32;
typedef __bf16 bf16x8 __attribute__((ext_vector_type(8)));
typedef float f32x4 __attribute__((ext_vector_type(4)));
typedef short s16x8 __attribute__((ext_vector_type(8)));
typedef u32 u32x4 __attribute__((ext_vector_type(4)));

// LDS stride in shorts: 72 = 36 dw == 4 (mod 32) -> bank-balanced b128 rows,
// rows 16B-aligned.
#define QS 72

// ws layout (u16): WtQ[64][128] @0, WtK @8192, WtV @16384,
//                  Wt1[64][64] @24576, Wt2 @28672. Total 32768 u16 = 64 KiB.
#define WSQ 0
#define WSK 8192
#define WSV 16384
#define WS1 24576
#define WS2 28672

__device__ inline u16 f2bf(float f) {             // fp32 -> bf16 RNE
    u32 x = __float_as_uint(f);
    x += 0x7fffu + ((x >> 16) & 1u);
    return (u16)(x >> 16);
}
__device__ inline bf16x8 ldf(const u16* p) { return *(const bf16x8*)p; }
__device__ inline bf16x8 zf8() {
    s16x8 z = {0, 0, 0, 0, 0, 0, 0, 0};
    return __builtin_bit_cast(bf16x8, z);
}
__device__ inline bf16x8 pack8(float4 a, float4 b) {
    s16x8 r;
    r[0] = (short)f2bf(a.x); r[1] = (short)f2bf(a.y);
    r[2] = (short)f2bf(a.z); r[3] = (short)f2bf(a.w);
    r[4] = (short)f2bf(b.x); r[5] = (short)f2bf(b.y);
    r[6] = (short)f2bf(b.z); r[7] = (short)f2bf(b.w);
    return __builtin_bit_cast(bf16x8, r);
}
// Token row permutation for kb storage (bits 5..0: b1 q1 q0 b0 r1 r0 ->
// b1 b0 q1 q0 r1 r0): score slot (ct,qd,r) then holds s = 8qd+4(ct&1)+r+32(ct>>1).
__device__ inline int kperm(int row) {
    return (row & 0x23) | ((row & 4) << 2) | ((row & 0x18) >> 1);
}

// 64x64 GEMM. A: registers (AREG, QKV) or LDS rows (FFN). B: global bf16
// Wt[col][KD] (L2-hot), ALL fragments loaded up-front (single vmem round).
// Wave w computes rows 16w..16w+15, 4 col-tiles.
// MODE 0: relu -> bf16 LDS row-major; MODE 1: relu -> bf16 LDS transposed
// (O[col][row], vectorized ushort4); MODE 2: no relu -> fp32 global
// (row stride N*D); MODE 3: relu -> bf16 LDS rows permuted by kperm (kb).
template<int KD, int MODE, bool AREG>
__device__ inline void gemm(const bf16x8* afr,
                            const u16* aLds, int As,
                            const u16* __restrict__ WtG,
                            const float* __restrict__ bias,
                            u16* O, int Os, float* G,
                            int w, int lane, float scale) {
    const int l15 = lane & 15, qd = lane >> 4;
    constexpr int NC = KD / 32;
    // -- batch: issue all B loads (and A LDS reads) before any MFMA --
    bf16x8 bfr[NC][4];
#pragma unroll
    for (int c = 0; c < NC; ++c)
#pragma unroll
        for (int ct = 0; ct < 4; ++ct)
            bfr[c][ct] = *(const bf16x8*)&WtG[(16 * ct + l15) * KD + c * 32 + qd * 8];
    bf16x8 afv[NC];
#pragma unroll
    for (int c = 0; c < NC; ++c)
        afv[c] = AREG ? afr[c]
                      : ldf(&aLds[(16 * w + l15) * As + c * 32 + qd * 8]);
    f32x4 acc[4] = {{0,0,0,0},{0,0,0,0},{0,0,0,0},{0,0,0,0}};
#pragma unroll
    for (int c = 0; c < NC; ++c)
#pragma unroll
        for (int ct = 0; ct < 4; ++ct)
            acc[ct] = __builtin_amdgcn_mfma_f32_16x16x32_bf16(afv[c], bfr[c][ct],
                                                              acc[ct], 0, 0, 0);
#pragma unroll
    for (int ct = 0; ct < 4; ++ct) {
        const int col = 16 * ct + l15;
        const float bv = bias[col];
        if (MODE == 1) {
            ushort4 st;
            st.x = f2bf(fmaxf(acc[ct][0] + bv, 0.f) * scale);
            st.y = f2bf(fmaxf(acc[ct][1] + bv, 0.f) * scale);
            st.z = f2bf(fmaxf(acc[ct][2] + bv, 0.f) * scale);
            st.w = f2bf(fmaxf(acc[ct][3] + bv, 0.f) * scale);
            *(ushort4*)&O[col * Os + 16 * w + 4 * qd] = st;
        } else {
#pragma unroll
            for (int r = 0; r < 4; ++r) {
                const int row = 16 * w + 4 * qd + r;
                float v = acc[ct][r] + bv;
                if (MODE != 2) v = fmaxf(v, 0.f);
                v *= scale;
                if (MODE == 0)      O[row * Os + col] = f2bf(v);
                else if (MODE == 3) O[kperm(row) * Os + col] = f2bf(v);
                else                G[(size_t)row * (Nn * Dd) + col] = v;
            }
        }
    }
}

// One-time weight transpose+convert: Wt[c][k] = bf16(W[k][c]).
__global__ __launch_bounds__(256)
void prep_w(const float* __restrict__ Wq, const float* __restrict__ Wk,
            const float* __restrict__ Wv, const float* __restrict__ W1,
            const float* __restrict__ W2, u16* __restrict__ ws) {
    int i = blockIdx.x * 256 + threadIdx.x;
    if (i < 24576) {                       // Wq/Wk/Wv: [128][64] each
        int m = i >> 13;
        int r = i & 8191;                  // r = k*64 + c (coalesced read)
        int k = r >> 6, c = r & 63;
        const float* W = (m == 0) ? Wq : (m == 1) ? Wk : Wv;
        ws[m * 8192 + c * 128 + k] = f2bf(W[r]);
    } else if (i < 32768) {                // W1/W2: [64][64] each
        int j = i - 24576;
        int m = j >> 12;
        int r = j & 4095;
        int k = r >> 6, c = r & 63;
        const float* W = (m == 0) ? W1 : W2;
        ws[24576 + m * 4096 + c * 64 + k] = f2bf(W[r]);
    }
}

__global__ __launch_bounds__(256, 4)
void ta_fused_kernel(const float* __restrict__ x,  const float* __restrict__ ste,
                     const float* __restrict__ bq, const float* __restrict__ bk,
                     const float* __restrict__ bv, const float* __restrict__ b1,
                     const float* __restrict__ b2, const u16* __restrict__ ws,
                     float* __restrict__ out) {
    // LDS map (shorts), 18432 total = 36,864 B -> 4 blocks/CU:
    //   qb [64][72] @ 0      (FFN abuf overlays after attention: qb accesses
    //                         are strictly wave-local rows, in-order per wave)
    //   kb [64][72] @ 4608   (rows kperm-permuted)
    //   vT [64][72] @ 9216   (vT[dim][s]; read-only after barrier)
    //   ao [64][72] @ 13824  (attention output, wave-local rows)
    __shared__ __align__(16) u16 sm[18432];
    u16* qb = sm;
    u16* kb = sm + 4608;
    u16* vT = sm + 9216;
    u16* ao = sm + 13824;

    const int tid  = threadIdx.x;
    const int w    = tid >> 6;
    const int lane = tid & 63;
    const int l15  = lane & 15, qd = lane >> 4;
    const int bid  = blockIdx.x;
    const int b = bid >> 9, n = bid & 511;

    // ---- Phase 0: A-fragments (concat(x,ste) row 16w+l15) -> registers ----
    const int trow = 16 * w + l15;
    const float* xr = x   + (((size_t)b * Tt + trow) * Nn + n) * Dd;
    const float* sr = ste + (((size_t)b * Tt + trow) * Nn + n) * Dd;
    bf16x8 af[4];
#pragma unroll
    for (int c = 0; c < 2; ++c) {
        float4 p0 = *(const float4*)(xr + c * 32 + qd * 8);
        float4 p1 = *(const float4*)(xr + c * 32 + qd * 8 + 4);
        af[c] = pack8(p0, p1);
    }
#pragma unroll
    for (int c = 0; c < 2; ++c) {
        float4 p0 = *(const float4*)(sr + c * 32 + qd * 8);
        float4 p1 = *(const float4*)(sr + c * 32 + qd * 8 + 4);
        af[c + 2] = pack8(p0, p1);
    }

    // ---- Phase 1: QKV (B-fragments from global bf16 Wt, L2-hot) ----
    // 1/sqrt(8) folded into q.
    gemm<128, 0, true>(af, nullptr, 0, ws + WSQ, bq, qb, QS, nullptr, w, lane,
                       0.35355339059327373f);
    gemm<128, 3, true>(af, nullptr, 0, ws + WSK, bk, kb, QS, nullptr, w, lane, 1.f);
    gemm<128, 1, true>(af, nullptr, 0, ws + WSV, bv, vT, QS, nullptr, w, lane, 1.f);
    __syncthreads();   // the ONLY barrier: kb/vT read cross-wave below

    // ---- Phase 2: attention. Wave w owns t-rows 16w..16w+15, all 8 heads.
    const bf16x8 z8 = zf8();
    const int ctmax = (w >= 2) ? 3 : 1;     // causal tile skip
    // software pipeline: preload head 0's q/k fragments
    bf16x8 qf = (qd == 0) ? ldf(&qb[(16 * w + l15) * QS]) : z8;
    bf16x8 kf[4];
#pragma unroll
    for (int ct = 0; ct < 4; ++ct)
        kf[ct] = (ct <= ctmax && qd == 0) ? ldf(&kb[(16 * ct + l15) * QS]) : z8;
#pragma unroll 1
    for (int h8 = 0; h8 < 64; h8 += 8) {
        // V loads for THIS iter (independent of P -> overlap with everything)
        const int vrow = h8 + (l15 & 7);
        bf16x8 va0 = ldf(&vT[vrow * QS + 0 + qd * 8]);
        bf16x8 va1 = z8;
        if (w >= 2) va1 = ldf(&vT[vrow * QS + 32 + qd * 8]);
        // scores (swapped): sv[ct] = mfma(A=k-tile ct, B=q). Output col l15 =
        // t-local, slot (ct,qd,r) -> s = 8qd+4(ct&1)+r+32(ct>>1) via kperm.
        f32x4 sv[4] = {{0,0,0,0},{0,0,0,0},{0,0,0,0},{0,0,0,0}};
#pragma unroll
        for (int ct = 0; ct < 4; ++ct)
            if (ct <= ctmax)
                sv[ct] = __builtin_amdgcn_mfma_f32_16x16x32_bf16(kf[ct], qf,
                                                                 sv[ct], 0, 0, 0);
        // prefetch NEXT iter's q/k fragments (hide LDS latency under exp/PV)
        bf16x8 qfn = z8, kfn[4] = {z8, z8, z8, z8};
        if (h8 < 56) {
            qfn = (qd == 0) ? ldf(&qb[(16 * w + l15) * QS + h8 + 8]) : z8;
#pragma unroll
            for (int ct = 0; ct < 4; ++ct)
                kfn[ct] = (ct <= ctmax && qd == 0)
                              ? ldf(&kb[(16 * ct + l15) * QS + h8 + 8]) : z8;
        }
        // mask + exp in-register (scores small: no max-subtraction; masked
        // entries exactly 0), pack to bf16 pairs (P fragment).
        const int t = 16 * w + l15;
        float dsum = 0.f;
        u32 pk[8];
#pragma unroll
        for (int ct = 0; ct < 4; ++ct) {
            if (ct <= ctmax) {
                const int sbase = 8 * qd + 4 * (ct & 1) + 32 * (ct >> 1);
#pragma unroll
                for (int r = 0; r < 4; ++r) {
                    float e = (sbase + r <= t) ? __expf(sv[ct][r]) : 0.f;
                    sv[ct][r] = e;
                    dsum += e;
                }
                pk[2 * ct]     = (u32)f2bf(sv[ct][0]) | ((u32)f2bf(sv[ct][1]) << 16);
                pk[2 * ct + 1] = (u32)f2bf(sv[ct][2]) | ((u32)f2bf(sv[ct][3]) << 16);
            } else {
                pk[2 * ct] = 0; pk[2 * ct + 1] = 0;
            }
        }
        // full row-denominator for t = 16w+l15: partial + cross-quad butterfly
        dsum += __shfl_xor(dsum, 16, 64);
        dsum += __shfl_xor(dsum, 32, 64);

        // PV (swapped): o = mfma(A = V^T slice, B = P^T). A[row=l15] = V-col
        // for dim h8+(l15&7) (rows 8..15 duplicate 0..7, discarded); B col
        // l15 = t -> lane's own dsum normalizes its column.
        f32x4 o = {0, 0, 0, 0};
        {
            u32x4 pb0 = {pk[0], pk[1], pk[2], pk[3]};
            o = __builtin_amdgcn_mfma_f32_16x16x32_bf16(
                    va0, __builtin_bit_cast(bf16x8, pb0), o, 0, 0, 0);
        }
        if (w >= 2) {
            u32x4 pb1 = {pk[4], pk[5], pk[6], pk[7]};
            o = __builtin_amdgcn_mfma_f32_16x16x32_bf16(
                    va1, __builtin_bit_cast(bf16x8, pb1), o, 0, 0, 0);
        }
        // o[r] = out[t=16w+l15][h8 + ((4qd+r)&7)] unnormalized; qd>=2 lanes
        // hold duplicates of qd-2. One aligned ushort4 store per lane.
        float invd = __builtin_amdgcn_rcpf(dsum);
        if (qd < 2) {
            ushort4 st;
            st.x = f2bf(o[0] * invd);
            st.y = f2bf(o[1] * invd);
            st.z = f2bf(o[2] * invd);
            st.w = f2bf(o[3] * invd);
            *(ushort4*)&ao[(16 * w + l15) * QS + h8 + 4 * qd] = st;
        }
        // rotate pipeline registers
        qf = qfn;
#pragma unroll
        for (int ct = 0; ct < 4; ++ct) kf[ct] = kfn[ct];
    }
    // No barrier: FFN A-operands are the wave's own ao rows; abuf overlays
    // qb whose reads/writes are strictly wave-local and in-order per wave;
    // vT is never written again.

    // ---- Phase 3: FFN ----
    u16* abuf = qb;
    gemm<64, 0, false>(nullptr, ao, QS, ws + WS1, b1, abuf, QS, nullptr,
                       w, lane, 1.f);
    float* ob = out + (((size_t)b * Tt) * Nn + n) * Dd;
    gemm<64, 2, false>(nullptr, abuf, QS, ws + WS2, b2, nullptr, 0, ob,
                       w, lane, 1.f);
}

extern "C" void kernel_launch(void* const* d_in, const int* in_sizes, int n_in,
                              void* d_out, int out_size, void* d_ws, size_t ws_size,
                              hipStream_t stream) {
    const float* x   = (const float*)d_in[0];
    const float* ste = (const float*)d_in[1];
    const float* Wq  = (const float*)d_in[2];
    const float* bq  = (const float*)d_in[3];
    const float* Wk  = (const float*)d_in[4];
    const float* bk  = (const float*)d_in[5];
    const float* Wv  = (const float*)d_in[6];
    const float* bv  = (const float*)d_in[7];
    const float* W1  = (const float*)d_in[8];
    const float* b1  = (const float*)d_in[9];
    const float* W2  = (const float*)d_in[10];
    const float* b2  = (const float*)d_in[11];
    float* out = (float*)d_out;
    u16* ws = (u16*)d_ws;

    hipLaunchKernelGGL(prep_w, dim3(128), dim3(256), 0, stream,
                       Wq, Wk, Wv, W1, W2, ws);
    hipLaunchKernelGGL(ta_fused_kernel, dim3(Bb * Nn), dim3(256), 0, stream,
                       x, ste, bq, bk, bv, b1, b2, ws, out);
}